// Round 10
// baseline (199.857 us; speedup 1.0000x reference)
//
#include <hip/hip_runtime.h>

#define BATCH 2
#define SS    256   // 16x16 subdomain grid
#define CC    128
#define HWN   256   // 16x16 spatial
#define FDIM  4096  // 64 ch * 8 * 8 per head
#define HS    (SS * FDIM)   // elements per head slice

typedef unsigned int uint;
typedef unsigned short ushort;
typedef short bf16x8 __attribute__((ext_vector_type(8)));
typedef ushort us4 __attribute__((ext_vector_type(4)));
typedef float f32x4 __attribute__((ext_vector_type(4)));

__device__ __forceinline__ ushort f2b(float f) {
  uint u = __float_as_uint(f);
  return (ushort)((u + 0x7fffu + ((u >> 16) & 1u)) >> 16);  // RNE
}
__device__ __forceinline__ float b2f(ushort h) { return __uint_as_float((uint)h << 16); }

// ---------------- K1: qkv projection (round-5 shape, dual output layout) -----
// Grid 512 x 512 thr, 8 waves, 2 column sets/wave (proven optimum).
// V (qkvi==2) stored in the old f' layout (k_out depends on it).
// Q,K (qkvi<2) stored in TILE layout: idx(s,f) = sy*65536 + (f>>3)*128
//   + sx*8 + (f&7)  -> k_scores wave loads become single 1-KB segments.
// Since this is a transpose-on-store (8-B pieces at 256-B stride), the block
// swizzle bs=(g&7)*64+g>>3 puts all 16 sx-siblings (writers of each 256-B
// line) on ONE XCD, co-resident -> L2 write-merge, no HBM amplification.
__global__ __launch_bounds__(512, 4) void k_qkv(const float* __restrict__ seq,
                                                const float* __restrict__ wqkv,
                                                ushort* __restrict__ qkvh) {
  __shared__ ushort wlds[128 * 128];   // 32 KB, XOR-swizzled 16-B blocks
  const int g = blockIdx.x;
  const int bs = (g & 7) * 64 + (g >> 3);   // XCD swizzle (bijective, 512%8==0)
  const int b = bs >> 8, s = bs & 255;
  const int sy = s >> 4, sx = s & 15;
  const int t = threadIdx.x;
  const int wv = t >> 6, lane = t & 63;
  const int qq = lane >> 4, m = lane & 15;

  const float* sp = seq + (size_t)bs * (CC * HWN);

  // B fragments: this wave's 2 column groups (ntg = wv*2 + set).
  // bfrag[set][ks] elem j = bf16(seq[c = ks*32+qq*8+j][hw = ntg*16+m])
  bf16x8 bfrag[2][4];
  uint oq[2], ov[2];
  #pragma unroll
  for (int set = 0; set < 2; ++set) {
    const int ntg = wv * 2 + set;
    const int hw = ntg * 16 + m;
    #pragma unroll
    for (int ks = 0; ks < 4; ++ks) {
      const int k0 = ks * 32 + qq * 8;
      float tmp[8];
      #pragma unroll
      for (int j = 0; j < 8; ++j) tmp[j] = sp[(k0 + j) * HWN + hw];
      bf16x8 fr;
      #pragma unroll
      for (int j = 0; j < 8; ++j) fr[j] = (short)f2b(tmp[j]);
      bfrag[set][ks] = fr;
    }
    const int n_qk = ((ntg >> 3) * 2 + (m >> 3)) * 2;
    const int hwl  = (ntg & 7) * 8 + (m & 7);
    // old layout (V): f' = m4*1024 + hwl*16 + qq*4 + r
    ov[set] = (uint)(((b * 8 + n_qk) * SS + s) * FDIM + hwl * 16 + qq * 4);
    // tile layout (Q,K): f0 = m4*1024 + hwl*16 + qq*4 ->
    // idx = sy*65536 + m4*16384 + hwl*256 + (qq>>1)*128 + sx*8 + (qq&1)*4
    oq[set] = (uint)((b * 8 + n_qk) * HS + sy * 65536 + hwl * 256
                     + (qq >> 1) * 128 + sx * 8 + (qq & 1) * 4);
  }

  for (int qkvi = 0; qkvi < 3; ++qkvi) {
    if (qkvi) __syncthreads();   // previous phase's LDS reads done
    // Stage this qkvi's 128x128 weight slice into LDS, converting f32->bf16.
    #pragma unroll
    for (int i = 0; i < 4; ++i) {
      const int row = i * 32 + (t >> 4), col16 = t & 15;
      const float* wp = wqkv + (size_t)(qkvi * 128 + row) * 128 + col16 * 8;
      f32x4 w0 = *(const f32x4*)(wp);
      f32x4 w1 = *(const f32x4*)(wp + 4);
      bf16x8 fr;
      #pragma unroll
      for (int e = 0; e < 4; ++e) { fr[e] = (short)f2b(w0[e]); fr[4 + e] = (short)f2b(w1[e]); }
      *(bf16x8*)&wlds[row * 128 + ((col16 ^ (row & 15)) * 8)] = fr;
    }
    __syncthreads();

    #pragma unroll
    for (int mt8 = 0; mt8 < 8; ++mt8) {
      bf16x8 afrag[4];
      #pragma unroll
      for (int ks = 0; ks < 4; ++ks)
        afrag[ks] = *(const bf16x8*)&wlds[(mt8 * 16 + m) * 128 + (((ks * 4 + qq) ^ m) * 8)];
      const int ch = mt8 >> 2, m4 = mt8 & 3;
      #pragma unroll
      for (int set = 0; set < 2; ++set) {
        f32x4 acc = {0.f, 0.f, 0.f, 0.f};
        #pragma unroll
        for (int ks = 0; ks < 4; ++ks)
          acc = __builtin_amdgcn_mfma_f32_16x16x32_bf16(afrag[ks], bfrag[set][ks], acc, 0, 0, 0);
        us4 pk;
        #pragma unroll
        for (int r = 0; r < 4; ++r) pk[r] = f2b(acc[r]);
        const uint off = (qkvi < 2)
            ? oq[set] + (uint)((qkvi * 16 + ch) * HS + m4 * 16384)
            : ov[set] + (uint)((32 + ch) * HS + m4 * 1024);
        *(us4*)(qkvh + off) = pk;
      }
    }
  }
}

// ---------------- K2: MFMA scores + softmax (tile-layout Q/K reads) ----------
// Same convoy structure as round 0; ONLY the Q/K addressing changed: a wave's
// 64 lanes now read one contiguous 1-KB segment per load (was 64 scattered
// 16-B requests at 8-KB stride) -> transaction count /64.
__global__ __launch_bounds__(1024) void k_scores(const ushort* __restrict__ qkvh,
                                                 float* __restrict__ attn) {
  __shared__ float red[16][64][12];
  const int g = blockIdx.x;
  const int unit = (g & 7) * 32 + (g >> 3);   // XCD swizzle
  const int b  = unit >> 7;
  const int n  = (unit >> 4) & 7;
  const int sy = unit & 15;
  const int t = threadIdx.x;
  const int wave = t >> 6, lane = t & 63;
  const int qq = lane >> 4, l15 = lane & 15;
  const ushort* qb = qkvh + (size_t)(b * 8 + n) * HS;
  const ushort* kb = qkvh + (size_t)(16 + b * 8 + n) * HS;

  // tile layout: elem(s,f) = sy*65536 + (f>>3)*128 + sx*8 + (f&7)
  const ushort* qp = qb + sy * 65536 + qq * 128 + l15 * 8;
  const ushort* kp[3];
  #pragma unroll
  for (int tl = 0; tl < 3; ++tl) {
    const int tyc = min(max(sy - 1 + tl, 0), 15);
    kp[tl] = kb + tyc * 65536 + qq * 128 + l15 * 8;
  }

  f32x4 acc[3] = {{0,0,0,0},{0,0,0,0},{0,0,0,0}};
  const int kbeg = wave * 256;
  #pragma unroll
  for (int it = 0; it < 4; ++it) {
    const int k0 = kbeg + it * 64;
    const int koff = k0 * 16;              // (k0>>3)*128
    bf16x8 a0 = *(const bf16x8*)(qp + koff);
    bf16x8 a1 = *(const bf16x8*)(qp + koff + 512);
    bf16x8 b0[3], b1[3];
    #pragma unroll
    for (int tl = 0; tl < 3; ++tl) {
      b0[tl] = *(const bf16x8*)(kp[tl] + koff);
      b1[tl] = *(const bf16x8*)(kp[tl] + koff + 512);
    }
    #pragma unroll
    for (int tl = 0; tl < 3; ++tl)
      acc[tl] = __builtin_amdgcn_mfma_f32_16x16x32_bf16(a0, b0[tl], acc[tl], 0, 0, 0);
    #pragma unroll
    for (int tl = 0; tl < 3; ++tl)
      acc[tl] = __builtin_amdgcn_mfma_f32_16x16x32_bf16(a1, b1[tl], acc[tl], 0, 0, 0);
  }

  #pragma unroll
  for (int tl = 0; tl < 3; ++tl)
    #pragma unroll
    for (int r = 0; r < 4; ++r) red[wave][lane][tl * 4 + r] = acc[tl][r];
  __syncthreads();
  if (t < 768) {
    const int lane2 = t / 12, idx = t - lane2 * 12;
    float ssum = red[0][lane2][idx];
    #pragma unroll
    for (int w = 1; w < 16; ++w) ssum += red[w][lane2][idx];
    red[0][lane2][idx] = ssum;
  }
  __syncthreads();
  if (wave != 0) return;
  #pragma unroll
  for (int tl = 0; tl < 3; ++tl)
    #pragma unroll
    for (int r = 0; r < 4; ++r) acc[tl][r] = red[0][lane][tl * 4 + r];

  const int tx = l15;
  float sc[3][4];
  #pragma unroll
  for (int tl = 0; tl < 3; ++tl) {
    const int ty = sy - 1 + tl;
    const bool tyv = (ty >= 0 && ty < 16);
    #pragma unroll
    for (int r = 0; r < 4; ++r) {
      const int sx = qq * 4 + r;
      const bool v = tyv && (tx - sx <= 1) && (sx - tx <= 1);
      sc[tl][r] = v ? acc[tl][r] * (1.f / 64.f) : -1e30f;
    }
  }
  #pragma unroll
  for (int r = 0; r < 4; ++r) {
    float mx = fmaxf(fmaxf(sc[0][r], sc[1][r]), sc[2][r]);
    #pragma unroll
    for (int off = 1; off < 16; off <<= 1) mx = fmaxf(mx, __shfl_xor(mx, off));
    float p[3], sum = 0.f;
    #pragma unroll
    for (int tl = 0; tl < 3; ++tl) { p[tl] = __expf(sc[tl][r] - mx); sum += p[tl]; }
    #pragma unroll
    for (int off = 1; off < 16; off <<= 1) sum += __shfl_xor(sum, off);
    const float inv = 1.f / sum;
    const int sx = qq * 4 + r;
    const int s = sy * 16 + sx;
    #pragma unroll
    for (int tl = 0; tl < 3; ++tl) {
      const int ty = sy - 1 + tl;
      const int dxp = tx - sx + 1;
      if (ty >= 0 && ty < 16 && dxp >= 0 && dxp <= 2)
        attn[((size_t)(b * 8 + n) * SS + s) * 9 + tl * 3 + dxp] = p[tl] * inv;
    }
  }
}

// ---------------- K3: fused PV + out projection (round-0/5 version) ----------
// V is still in the old f' layout; this kernel is verbatim round 5.
__global__ __launch_bounds__(256) void k_out(const ushort* __restrict__ qkvh,
                                             const float* __restrict__ attn,
                                             const float* __restrict__ wout,
                                             const float* __restrict__ bout,
                                             float* __restrict__ out) {
  __shared__ ushort wlds[128 * 128];   // 32 KB, XOR-swizzled
  const int g = blockIdx.x;
  const int r9 = g >> 3;
  const int G = (g & 7) * 4 + (r9 >> 6);      // (b,sy) region, 0..31
  const int idx = r9 & 63;                     // 16 sx x 4 sub
  const int b = G >> 4, sy = G & 15;
  const int sx = idx >> 2, sub = idx & 3;
  const int s = sy * 16 + sx;
  const int bs = b * 256 + s;
  const int t = threadIdx.x;
  const int wave = t >> 6, lane = t & 63;
  const int ntg = sub * 4 + wave;
  const int qq = lane >> 4, m = lane & 15;

  // Stage wout into LDS with the cc' permutation + f32->bf16 conversion.
  {
    const int col16 = t & 15;
    const int ks = col16 >> 2, qw = col16 & 3;
    const int creal0 = (ks >> 1) * 64 + ((((ks & 1) << 1) | (qw >> 1)) << 4)
                       + ((qw & 1) << 3);
    #pragma unroll
    for (int i = 0; i < 8; ++i) {
      const int row = i * 16 + (t >> 4);
      const float* wp = wout + (size_t)row * 128 + creal0;
      f32x4 w0 = *(const f32x4*)(wp);
      f32x4 w1 = *(const f32x4*)(wp + 4);
      bf16x8 fr;
      #pragma unroll
      for (int e = 0; e < 4; ++e) { fr[e] = (short)f2b(w0[e]); fr[4 + e] = (short)f2b(w1[e]); }
      *(bf16x8*)&wlds[row * 128 + ((col16 ^ (row & 15)) * 8)] = fr;
    }
  }

  int sjc[9];
  bool vld[9];
  #pragma unroll
  for (int j = 0; j < 9; ++j) {
    const int ny = sy + j / 3 - 1, nx = sx + j % 3 - 1;
    vld[j] = (ny >= 0 && ny < 16 && nx >= 0 && nx < 16);
    sjc[j] = min(max(ny, 0), 15) * 16 + min(max(nx, 0), 15);
  }

  const int nbase = ((ntg >> 3) * 2 + (m >> 3)) * 2;  // + ch
  float pch[2][9];
  #pragma unroll
  for (int ch = 0; ch < 2; ++ch) {
    #pragma unroll
    for (int j = 0; j < 9; ++j) {
      const float w = attn[((size_t)(b * 8 + nbase + ch) * SS + s) * 9 + j];
      pch[ch][j] = vld[j] ? w : 0.f;
    }
  }

  // sa in MFMA B-fragment layout; unified v layout -> 4 x 256-B segments/load
  const int hwl = (ntg & 7) * 8 + (m & 7);
  bf16x8 bfrag[4];
  #pragma unroll
  for (int ks = 0; ks < 4; ++ks) {
    const int ch = ks >> 1;
    const int c64hi = ((ks & 1) << 1) | (qq >> 1);
    const int half = qq & 1;
    const ushort* vb = qkvh + (size_t)(32 + b * 8 + nbase + ch) * HS;
    const int off = c64hi * 1024 + hwl * 16 + half * 8;
    float facc[8] = {0.f, 0.f, 0.f, 0.f, 0.f, 0.f, 0.f, 0.f};
    #pragma unroll
    for (int j = 0; j < 9; ++j) {
      bf16x8 vv = *(const bf16x8*)(vb + (size_t)sjc[j] * FDIM + off);
      const float pj = pch[ch][j];
      #pragma unroll
      for (int e = 0; e < 8; ++e) facc[e] += pj * b2f((ushort)vv[e]);
    }
    bf16x8 fr;
    #pragma unroll
    for (int e = 0; e < 8; ++e) fr[e] = (short)f2b(facc[e]);
    bfrag[ks] = fr;
  }

  __syncthreads();   // staging complete before afrag reads

  // out[d][hw] = wout_perm[d][cc'] @ sa[cc'][hw] + bout[d]
  #pragma unroll
  for (int mt = 0; mt < 8; ++mt) {
    bf16x8 afrag[4];
    #pragma unroll
    for (int ks = 0; ks < 4; ++ks)
      afrag[ks] = *(const bf16x8*)&wlds[(mt * 16 + m) * 128 + (((ks * 4 + qq) ^ m) * 8)];
    f32x4 acc = {0.f, 0.f, 0.f, 0.f};
    #pragma unroll
    for (int ks = 0; ks < 4; ++ks)
      acc = __builtin_amdgcn_mfma_f32_16x16x32_bf16(afrag[ks], bfrag[ks], acc, 0, 0, 0);
    const int hw = ntg * 16 + m;
    #pragma unroll
    for (int r = 0; r < 4; ++r) {
      const int d = mt * 16 + qq * 4 + r;
      out[((size_t)bs * CC + d) * HWN + hw] = acc[r] + bout[d];
    }
  }
}

extern "C" void kernel_launch(void* const* d_in, const int* in_sizes, int n_in,
                              void* d_out, int out_size, void* d_ws, size_t ws_size,
                              hipStream_t stream) {
  const float* seq  = (const float*)d_in[0];
  const float* wqkv = (const float*)d_in[1];
  const float* wout = (const float*)d_in[2];
  const float* bout = (const float*)d_in[3];
  char* ws = (char*)d_ws;
  // ws layout (bytes): qkvh 100663296 | attn 147456
  ushort* qkvh = (ushort*)(ws);
  float*  attn = (float*)(ws + 100663296ull);
  float*  outp = (float*)d_out;

  hipLaunchKernelGGL(k_qkv,    dim3(512),  dim3(512),  0, stream, seq, wqkv, qkvh);
  hipLaunchKernelGGL(k_scores, dim3(256),  dim3(1024), 0, stream, qkvh, attn);
  hipLaunchKernelGGL(k_out,    dim3(2048), dim3(256),  0, stream, qkvh, attn, wout, bout, outp);
}

// Round 11
// 193.041 us; speedup vs baseline: 1.0353x; 1.0353x over previous
//
#include <hip/hip_runtime.h>

#define BATCH 2
#define SS    256   // 16x16 subdomain grid
#define CC    128
#define HWN   256   // 16x16 spatial
#define FDIM  4096  // 64 ch * 8 * 8 per head

typedef unsigned int uint;
typedef unsigned short ushort;
typedef short bf16x8 __attribute__((ext_vector_type(8)));
typedef ushort us4 __attribute__((ext_vector_type(4)));
typedef float f32x4 __attribute__((ext_vector_type(4)));

__device__ __forceinline__ ushort f2b(float f) {
  uint u = __float_as_uint(f);
  return (ushort)((u + 0x7fffu + ((u >> 16) & 1u)) >> 16);  // RNE
}
__device__ __forceinline__ float b2f(ushort h) { return __uint_as_float((uint)h << 16); }

// ---------------- K1: qkv projection (round-5 exact, measured 48.5 us) -------
// Grid: 512 blocks (one per bs), 512 threads = 8 waves, each wave owns 2
// column sets (N=32). Weights converted f32->bf16 inline during staging.
// Store layout: qkvh[(qkvi*16+b*8+n)][s][f'], f' = (c>>4)*1024 + hwl*16 + (c&15)
__global__ __launch_bounds__(512, 4) void k_qkv(const float* __restrict__ seq,
                                                const float* __restrict__ wqkv,
                                                ushort* __restrict__ qkvh) {
  __shared__ ushort wlds[128 * 128];   // 32 KB, XOR-swizzled 16-B blocks
  const int bs = blockIdx.x;
  const int b = bs >> 8, s = bs & 255;
  const int t = threadIdx.x;
  const int wv = t >> 6, lane = t & 63;
  const int qq = lane >> 4, m = lane & 15;

  const float* sp = seq + (size_t)bs * (CC * HWN);

  bf16x8 bfrag[2][4];
  uint obase[2];
  #pragma unroll
  for (int set = 0; set < 2; ++set) {
    const int ntg = wv * 2 + set;
    const int hw = ntg * 16 + m;
    #pragma unroll
    for (int ks = 0; ks < 4; ++ks) {
      const int k0 = ks * 32 + qq * 8;
      float tmp[8];
      #pragma unroll
      for (int j = 0; j < 8; ++j) tmp[j] = sp[(k0 + j) * HWN + hw];
      bf16x8 fr;
      #pragma unroll
      for (int j = 0; j < 8; ++j) fr[j] = (short)f2b(tmp[j]);
      bfrag[set][ks] = fr;
    }
    const int n_qk = ((ntg >> 3) * 2 + (m >> 3)) * 2;
    const int hwl  = (ntg & 7) * 8 + (m & 7);
    obase[set] = (uint)(((b * 8 + n_qk) * SS + s) * FDIM + hwl * 16 + qq * 4);
  }

  for (int qkvi = 0; qkvi < 3; ++qkvi) {
    if (qkvi) __syncthreads();
    #pragma unroll
    for (int i = 0; i < 4; ++i) {
      const int row = i * 32 + (t >> 4), col16 = t & 15;
      const float* wp = wqkv + (size_t)(qkvi * 128 + row) * 128 + col16 * 8;
      f32x4 w0 = *(const f32x4*)(wp);
      f32x4 w1 = *(const f32x4*)(wp + 4);
      bf16x8 fr;
      #pragma unroll
      for (int e = 0; e < 4; ++e) { fr[e] = (short)f2b(w0[e]); fr[4 + e] = (short)f2b(w1[e]); }
      *(bf16x8*)&wlds[row * 128 + ((col16 ^ (row & 15)) * 8)] = fr;
    }
    __syncthreads();

    #pragma unroll
    for (int mt8 = 0; mt8 < 8; ++mt8) {
      bf16x8 afrag[4];
      #pragma unroll
      for (int ks = 0; ks < 4; ++ks)
        afrag[ks] = *(const bf16x8*)&wlds[(mt8 * 16 + m) * 128 + (((ks * 4 + qq) ^ m) * 8)];
      const int ch = mt8 >> 2, m4 = mt8 & 3;
      #pragma unroll
      for (int set = 0; set < 2; ++set) {
        f32x4 acc = {0.f, 0.f, 0.f, 0.f};
        #pragma unroll
        for (int ks = 0; ks < 4; ++ks)
          acc = __builtin_amdgcn_mfma_f32_16x16x32_bf16(afrag[ks], bfrag[set][ks], acc, 0, 0, 0);
        us4 pk;
        #pragma unroll
        for (int r = 0; r < 4; ++r) pk[r] = f2b(acc[r]);
        *(us4*)(qkvh + obase[set]
                + (uint)((qkvi * 16 + ch) * (SS * FDIM) + m4 * 1024)) = pk;
      }
    }
  }
}

// ---------------- K2: MFMA scores + softmax, LDS-staged ----------------------
// Fixes the 8-KB-lane-stride Q/K loads LOCALLY (qkvh layout untouched):
// block (b,n,sy) x 256 thr; 16 f-chunks of 256, double-buffered 32 KB LDS
// tiles (Q 16 rows + K 48 rows, 512-B contiguous coalesced staging,
// slot^=(r&7) swizzle -> conflict-free b128 fragment reads). Chunk c computed
// by wave c>>2 (acc persists over its 1024-f slice), overlapped with staging
// c+1. 4-partial reduce + identical mask/softmax tail.
__global__ __launch_bounds__(256) void k_scores(const ushort* __restrict__ qkvh,
                                                float* __restrict__ attn) {
  __shared__ ushort sq[2][64 * 256];   // 2 x 32 KB staged tiles
  __shared__ float red[4][64][12];
  const int g = blockIdx.x;
  const int unit = (g & 7) * 32 + (g >> 3);   // XCD swizzle
  const int b  = unit >> 7;
  const int n  = (unit >> 4) & 7;
  const int sy = unit & 15;
  const int t = threadIdx.x;
  const int wave = t >> 6, lane = t & 63;
  const int qq = lane >> 4, l15 = lane & 15;
  const size_t hs = (size_t)SS * FDIM;
  const ushort* qb = qkvh + (size_t)(b * 8 + n) * hs;
  const ushort* kb = qkvh + (size_t)(16 + b * 8 + n) * hs;

  // staging: thread owns rows r = (t>>5)+8i, 16-B slot = t&31 (512 B/row)
  const int r0 = t >> 5, slot = t & 31;
  const ushort* rowsrc[8];
  uint dst[8];
  #pragma unroll
  for (int i = 0; i < 8; ++i) {
    const int r = r0 + 8 * i;
    const ushort* base = (r < 16)
      ? qb + (size_t)(sy * 16 + r) * FDIM
      : kb + (size_t)(min(max(sy - 1 + ((r - 16) >> 4), 0), 15) * 16 + (r & 15)) * FDIM;
    rowsrc[i] = base + slot * 8;
    dst[i] = (uint)(r * 512 + ((slot ^ (r & 7)) * 16));
  }

  f32x4 acc[3] = {{0,0,0,0},{0,0,0,0},{0,0,0,0}};

  // prologue: stage chunk 0
  #pragma unroll
  for (int i = 0; i < 8; ++i)
    *(bf16x8*)((char*)sq[0] + dst[i]) = *(const bf16x8*)(rowsrc[i]);
  __syncthreads();

  for (int c = 0; c < 16; ++c) {
    const int buf = c & 1;
    if (c < 15) {                      // stage next chunk into other buffer
      #pragma unroll
      for (int i = 0; i < 8; ++i)
        *(bf16x8*)((char*)sq[buf ^ 1] + dst[i]) =
            *(const bf16x8*)(rowsrc[i] + (c + 1) * 256);
    }
    if ((c >> 2) == wave) {            // this wave owns f-slice of chunk c
      const char* base = (const char*)sq[buf];
      #pragma unroll
      for (int k = 0; k < 8; ++k) {
        const int sl = k * 4 + qq;     // f_local = sl*8
        bf16x8 a = *(const bf16x8*)(base + l15 * 512 + ((sl ^ (l15 & 7)) * 16));
        #pragma unroll
        for (int tl = 0; tl < 3; ++tl) {
          const int r = 16 + tl * 16 + l15;
          bf16x8 bb = *(const bf16x8*)(base + r * 512 + ((sl ^ (r & 7)) * 16));
          acc[tl] = __builtin_amdgcn_mfma_f32_16x16x32_bf16(a, bb, acc[tl], 0, 0, 0);
        }
      }
    }
    __syncthreads();
  }

  #pragma unroll
  for (int tl = 0; tl < 3; ++tl)
    #pragma unroll
    for (int r = 0; r < 4; ++r) red[wave][lane][tl * 4 + r] = acc[tl][r];
  __syncthreads();
  if (wave != 0) return;
  #pragma unroll
  for (int tl = 0; tl < 3; ++tl)
    #pragma unroll
    for (int r = 0; r < 4; ++r)
      acc[tl][r] = red[0][lane][tl * 4 + r] + red[1][lane][tl * 4 + r]
                 + red[2][lane][tl * 4 + r] + red[3][lane][tl * 4 + r];

  const int tx = l15;
  float sc[3][4];
  #pragma unroll
  for (int tl = 0; tl < 3; ++tl) {
    const int ty = sy - 1 + tl;
    const bool tyv = (ty >= 0 && ty < 16);
    #pragma unroll
    for (int r = 0; r < 4; ++r) {
      const int sx = qq * 4 + r;
      const bool v = tyv && (tx - sx <= 1) && (sx - tx <= 1);
      sc[tl][r] = v ? acc[tl][r] * (1.f / 64.f) : -1e30f;
    }
  }
  #pragma unroll
  for (int r = 0; r < 4; ++r) {
    float mx = fmaxf(fmaxf(sc[0][r], sc[1][r]), sc[2][r]);
    #pragma unroll
    for (int off = 1; off < 16; off <<= 1) mx = fmaxf(mx, __shfl_xor(mx, off));
    float p[3], sum = 0.f;
    #pragma unroll
    for (int tl = 0; tl < 3; ++tl) { p[tl] = __expf(sc[tl][r] - mx); sum += p[tl]; }
    #pragma unroll
    for (int off = 1; off < 16; off <<= 1) sum += __shfl_xor(sum, off);
    const float inv = 1.f / sum;
    const int sx = qq * 4 + r;
    const int s = sy * 16 + sx;
    #pragma unroll
    for (int tl = 0; tl < 3; ++tl) {
      const int ty = sy - 1 + tl;
      const int dxp = tx - sx + 1;
      if (ty >= 0 && ty < 16 && dxp >= 0 && dxp <= 2)
        attn[((size_t)(b * 8 + n) * SS + s) * 9 + tl * 3 + dxp] = p[tl] * inv;
    }
  }
}

// ---------------- K3: fused PV + out projection (round-5 exact) --------------
__global__ __launch_bounds__(256) void k_out(const ushort* __restrict__ qkvh,
                                             const float* __restrict__ attn,
                                             const float* __restrict__ wout,
                                             const float* __restrict__ bout,
                                             float* __restrict__ out) {
  __shared__ ushort wlds[128 * 128];   // 32 KB, XOR-swizzled
  const int g = blockIdx.x;
  const int r9 = g >> 3;
  const int G = (g & 7) * 4 + (r9 >> 6);      // (b,sy) region, 0..31
  const int idx = r9 & 63;                     // 16 sx x 4 sub
  const int b = G >> 4, sy = G & 15;
  const int sx = idx >> 2, sub = idx & 3;
  const int s = sy * 16 + sx;
  const int bs = b * 256 + s;
  const int t = threadIdx.x;
  const int wave = t >> 6, lane = t & 63;
  const int ntg = sub * 4 + wave;
  const int qq = lane >> 4, m = lane & 15;
  const size_t hs = (size_t)SS * FDIM;

  {
    const int col16 = t & 15;
    const int ks = col16 >> 2, qw = col16 & 3;
    const int creal0 = (ks >> 1) * 64 + ((((ks & 1) << 1) | (qw >> 1)) << 4)
                       + ((qw & 1) << 3);
    #pragma unroll
    for (int i = 0; i < 8; ++i) {
      const int row = i * 16 + (t >> 4);
      const float* wp = wout + (size_t)row * 128 + creal0;
      f32x4 w0 = *(const f32x4*)(wp);
      f32x4 w1 = *(const f32x4*)(wp + 4);
      bf16x8 fr;
      #pragma unroll
      for (int e = 0; e < 4; ++e) { fr[e] = (short)f2b(w0[e]); fr[4 + e] = (short)f2b(w1[e]); }
      *(bf16x8*)&wlds[row * 128 + ((col16 ^ (row & 15)) * 8)] = fr;
    }
  }

  int sjc[9];
  bool vld[9];
  #pragma unroll
  for (int j = 0; j < 9; ++j) {
    const int ny = sy + j / 3 - 1, nx = sx + j % 3 - 1;
    vld[j] = (ny >= 0 && ny < 16 && nx >= 0 && nx < 16);
    sjc[j] = min(max(ny, 0), 15) * 16 + min(max(nx, 0), 15);
  }

  const int nbase = ((ntg >> 3) * 2 + (m >> 3)) * 2;  // + ch
  float pch[2][9];
  #pragma unroll
  for (int ch = 0; ch < 2; ++ch) {
    #pragma unroll
    for (int j = 0; j < 9; ++j) {
      const float w = attn[((size_t)(b * 8 + nbase + ch) * SS + s) * 9 + j];
      pch[ch][j] = vld[j] ? w : 0.f;
    }
  }

  const int hwl = (ntg & 7) * 8 + (m & 7);
  bf16x8 bfrag[4];
  #pragma unroll
  for (int ks = 0; ks < 4; ++ks) {
    const int ch = ks >> 1;
    const int c64hi = ((ks & 1) << 1) | (qq >> 1);
    const int half = qq & 1;
    const ushort* vb = qkvh + (size_t)(32 + b * 8 + nbase + ch) * hs;
    const int off = c64hi * 1024 + hwl * 16 + half * 8;
    float facc[8] = {0.f, 0.f, 0.f, 0.f, 0.f, 0.f, 0.f, 0.f};
    #pragma unroll
    for (int j = 0; j < 9; ++j) {
      bf16x8 vv = *(const bf16x8*)(vb + (size_t)sjc[j] * FDIM + off);
      const float pj = pch[ch][j];
      #pragma unroll
      for (int e = 0; e < 8; ++e) facc[e] += pj * b2f((ushort)vv[e]);
    }
    bf16x8 fr;
    #pragma unroll
    for (int e = 0; e < 8; ++e) fr[e] = (short)f2b(facc[e]);
    bfrag[ks] = fr;
  }

  __syncthreads();   // staging complete before afrag reads

  #pragma unroll
  for (int mt = 0; mt < 8; ++mt) {
    bf16x8 afrag[4];
    #pragma unroll
    for (int ks = 0; ks < 4; ++ks)
      afrag[ks] = *(const bf16x8*)&wlds[(mt * 16 + m) * 128 + (((ks * 4 + qq) ^ m) * 8)];
    f32x4 acc = {0.f, 0.f, 0.f, 0.f};
    #pragma unroll
    for (int ks = 0; ks < 4; ++ks)
      acc = __builtin_amdgcn_mfma_f32_16x16x32_bf16(afrag[ks], bfrag[ks], acc, 0, 0, 0);
    const int hw = ntg * 16 + m;
    #pragma unroll
    for (int r = 0; r < 4; ++r) {
      const int d = mt * 16 + qq * 4 + r;
      out[((size_t)bs * CC + d) * HWN + hw] = acc[r] + bout[d];
    }
  }
}

extern "C" void kernel_launch(void* const* d_in, const int* in_sizes, int n_in,
                              void* d_out, int out_size, void* d_ws, size_t ws_size,
                              hipStream_t stream) {
  const float* seq  = (const float*)d_in[0];
  const float* wqkv = (const float*)d_in[1];
  const float* wout = (const float*)d_in[2];
  const float* bout = (const float*)d_in[3];
  char* ws = (char*)d_ws;
  // ws layout (bytes): qkvh 100663296 | attn 147456
  ushort* qkvh = (ushort*)(ws);
  float*  attn = (float*)(ws + 100663296ull);
  float*  outp = (float*)d_out;

  hipLaunchKernelGGL(k_qkv,    dim3(512),  dim3(512), 0, stream, seq, wqkv, qkvh);
  hipLaunchKernelGGL(k_scores, dim3(256),  dim3(256), 0, stream, qkvh, attn);
  hipLaunchKernelGGL(k_out,    dim3(2048), dim3(256), 0, stream, qkvh, attn, wout, bout, outp);
}